// Round 1
// baseline (254.175 us; speedup 1.0000x reference)
//
#include <hip/hip_runtime.h>
#include <math.h>

#define LOG2PI_F 1.8378770664093453f

// Fused single-pass kernel.
// Each block owns 32 pairs; 8 threads per pair (q-groups) split the 49
// quadrature points. gauss_pts are computed ONCE, staged in LDS in the
// final [pair][49][2] layout, and dumped with coalesced 16B-aligned
// float4 stores (32*98*4 = 12544 B per block, multiple of 16). The
// integral is accumulated from the same gx/gy and reduced via LDS.
// Inputs are read exactly once (old kernel read rot/trans twice).
__global__ __launch_bounds__(256) void gauss2d_fused(
    const float* __restrict__ tv_means,     // [B,2]
    const float* __restrict__ tv_covars,    // [B,2,2]
    const float* __restrict__ rotations,    // [B,2,2]
    const float* __restrict__ translations, // [B,2]
    const float* __restrict__ eta,          // [2,49]
    const float* __restrict__ weights,      // [49]
    float* __restrict__ gauss_pts,          // [B,49,2]
    float* __restrict__ integral,           // [B]
    unsigned int B)
{
    __shared__ float lds_pts[32 * 98];   // final layout, linear
    __shared__ float lds_s[8][32];       // per-group partial sums

    const unsigned int tid  = threadIdx.x;
    const unsigned int p    = tid & 31u;   // pair within block
    const unsigned int g    = tid >> 5u;   // q-group 0..7
    const unsigned int base = blockIdx.x * 32u;
    const unsigned int pg   = base + p;

    float s = 0.0f;
    if (pg < B) {
        const float4 R  = ((const float4*)rotations)[pg];    // R00,R01,R10,R11
        const float2 tr = ((const float2*)translations)[pg];
        const float2 mu = ((const float2*)tv_means)[pg];
        const float4 C  = ((const float4*)tv_covars)[pg];    // c00,c01,c10,c11

        const float det     = C.x * C.w - C.y * C.z;
        const float inv_det = 1.0f / det;
        const float lognorm = fmaf(-0.5f, __logf(det), -LOG2PI_F);
        const float c01p10  = C.y + C.z;

        // group g handles q = g, g+8, ..., (<49). Group 0 gets 7, rest 6.
        #pragma unroll
        for (unsigned int i = 0u; i < 7u; ++i) {
            const unsigned int q = g + (i << 3);
            if (q < 49u) {
                const float ex = eta[q];
                const float ey = eta[49u + q];
                const float gx = fmaf(R.x, ex, fmaf(R.y, ey, tr.x));
                const float gy = fmaf(R.z, ex, fmaf(R.w, ey, tr.y));
                *(float2*)(&lds_pts[p * 98u + (q << 1)]) = make_float2(gx, gy);
                const float dx = gx - mu.x;
                const float dy = gy - mu.y;
                const float quad =
                    (C.w * dx * dx - c01p10 * dx * dy + C.x * dy * dy) * inv_det;
                s += weights[q] * __expf(fmaf(-0.5f, quad, lognorm));
            }
        }
    }
    lds_s[g][p] = s;
    __syncthreads();

    // ---- coalesced float4 dump of gauss_pts ----
    const unsigned int npair = (base + 32u <= B) ? 32u : (B > base ? B - base : 0u);
    const unsigned int nfl   = npair * 98u;          // floats to write
    const unsigned int nf4   = nfl >> 2;             // full float4s
    float4* __restrict__ dst = (float4*)(gauss_pts + (size_t)base * 98u); // 16B aligned
    const float4* __restrict__ src = (const float4*)lds_pts;
    for (unsigned int k = tid; k < nf4; k += 256u) dst[k] = src[k];
    if ((nfl & 3u) && tid == 0u) {   // odd npair tail (2 floats)
        *(float2*)(gauss_pts + (size_t)base * 98u + (size_t)(nf4 << 2)) =
            *(const float2*)(&lds_pts[nf4 << 2]);
    }

    // ---- integral reduction: thread p sums its pair's 8 partials ----
    if (tid < 32u && pg < B) {   // p == tid here
        float t = 0.0f;
        #pragma unroll
        for (int gg = 0; gg < 8; ++gg) t += lds_s[gg][tid];
        integral[pg] = fminf(fmaxf(t, 0.0f), 1.0f);
    }
}

extern "C" void kernel_launch(void* const* d_in, const int* in_sizes, int n_in,
                              void* d_out, int out_size, void* d_ws, size_t ws_size,
                              hipStream_t stream) {
    const float* tv_means     = (const float*)d_in[0];
    const float* tv_covars    = (const float*)d_in[1];
    const float* rotations    = (const float*)d_in[2];
    const float* translations = (const float*)d_in[3];
    const float* eta          = (const float*)d_in[4];
    const float* weights      = (const float*)d_in[5];

    const unsigned int B = (unsigned int)(in_sizes[0] / 2);   // [B,2] means
    float* gauss_pts = (float*)d_out;                          // B*98 floats
    float* integral  = (float*)d_out + (size_t)B * 98u;        // then B floats

    dim3 grid((B + 31u) / 32u);
    dim3 block(256);
    hipLaunchKernelGGL(gauss2d_fused, grid, block, 0, stream,
                       tv_means, tv_covars, rotations, translations,
                       eta, weights, gauss_pts, integral, B);
}